// Round 9
// baseline (448.996 us; speedup 1.0000x reference)
//
#include <hip/hip_runtime.h>
#include <cstddef>

#define NN    100000
#define EE    3200000
#define GG    512
#define NBK2  391          // buckets of 256 nodes (single-pass sort)
#define BCAP  9216         // bucket capacity: mean 8192, +11 sigma
#define TT    4096         // LDS sort tile (edges)

typedef __attribute__((ext_vector_type(8))) short bf16x8;
typedef __attribute__((ext_vector_type(4))) float f32x4;
typedef __attribute__((ext_vector_type(8))) unsigned short u16x8;

struct U12 { unsigned a, b, c; };   // 12 B: 8 chans x 12-bit

static __device__ __forceinline__ unsigned short f2b(float f) {
  unsigned u = __float_as_uint(f);
  unsigned r = u + 0x7fffu + ((u >> 16) & 1u);   // RNE
  return (unsigned short)(r >> 16);
}

// ---------------- per-row |x| max + W1->bf16 (full-occupancy streaming) --------
__global__ __launch_bounds__(256) void k_rmax(const float* __restrict__ x,
                                              const float* __restrict__ w1,
                                              float* __restrict__ rmax,
                                              unsigned short* __restrict__ wbf) {
  const int tid  = threadIdx.x;
  const int wave = tid >> 6, lane = tid & 63;
  const int r0   = blockIdx.x * 16 + wave * 4;   // 6250 * 16 = 100000 exact
#pragma unroll
  for (int it = 0; it < 4; ++it) {
    int row = r0 + it;
    float4 v = ((const float4*)x)[(size_t)row * 64 + lane];
    float m = fmaxf(fmaxf(fabsf(v.x), fabsf(v.y)), fmaxf(fabsf(v.z), fabsf(v.w)));
#pragma unroll
    for (int k = 1; k < 64; k <<= 1) m = fmaxf(m, __shfl_xor(m, k, 64));
    if (lane == 0) rmax[row] = m;
  }
  if (blockIdx.x < 64) {               // W1 -> bf16
    int i = blockIdx.x * 256 + tid;
    float4 v = ((const float4*)w1)[i];
    ushort4 o;
    o.x = f2b(v.x); o.y = f2b(v.y); o.z = f2b(v.z); o.w = f2b(v.w);
    ((ushort4*)wbf)[i] = o;
  }
}

// ---------------- single-pass sort: edges -> 391 buckets, 1 tile per block -----
__global__ __launch_bounds__(1024, 2) void k_split(const int* __restrict__ src,
                                                   const int* __restrict__ dst,
                                                   int* __restrict__ gcur,
                                                   int* __restrict__ pk) {
  __shared__ int hist[NBK2], st[NBK2], cur[NBK2], gbase[NBK2];
  __shared__ int sc[512];
  __shared__ int sorted[TT];
  __shared__ unsigned short binof[TT];
  const int tid = threadIdx.x;
  const int t0  = blockIdx.x * TT;
  const int tc  = min(TT, EE - t0);

  if (tid < NBK2) hist[tid] = 0;
  __syncthreads();
  int myk[4], myw[4];
#pragma unroll
  for (int r = 0; r < 4; ++r) {
    int j = r * 1024 + tid;
    myk[r] = -1;
    if (j < tc) {
      int s = src[t0 + j], d = dst[t0 + j];
      myk[r] = s >> 8;                        // bucket of 256 nodes
      myw[r] = ((s & 255) << 17) | d;         // (src_local8, dst17)
      atomicAdd(&hist[myk[r]], 1);
    }
  }
  __syncthreads();
  if (tid < 512) sc[tid] = (tid < NBK2) ? hist[tid] : 0;
  __syncthreads();
  for (int d = 1; d < 512; d <<= 1) {
    int v = (tid < 512 && tid >= d) ? sc[tid - d] : 0;
    __syncthreads();
    if (tid < 512) sc[tid] += v;
    __syncthreads();
  }
  if (tid < NBK2) { st[tid] = tid ? sc[tid - 1] : 0; cur[tid] = st[tid]; }
  __syncthreads();
#pragma unroll
  for (int r = 0; r < 4; ++r) {
    if (myk[r] >= 0) {
      int pos = atomicAdd(&cur[myk[r]], 1);
      sorted[pos] = myw[r];
      binof[pos] = (unsigned short)myk[r];
    }
  }
  __syncthreads();
  if (tid < NBK2) {
    int c = cur[tid] - st[tid];
    gbase[tid] = c ? atomicAdd(&gcur[tid], c) : 0;
  }
  __syncthreads();
  for (int j = tid; j < tc; j += 1024) {
    int k   = binof[j];
    int idx = gbase[k] + (j - st[k]);
    if (idx < BCAP) pk[(size_t)k * BCAP + idx] = sorted[j];
  }
}

// ---------------- per-bucket prep: csr + ro + xm from rmax (no x pass) ---------
__global__ __launch_bounds__(512) void k_prep(const int* __restrict__ gcur,
                                              const int* __restrict__ pk,
                                              const float* __restrict__ rmax,
                                              int* __restrict__ csr,
                                              int* __restrict__ ro,
                                              int* __restrict__ xm) {
  __shared__ int hist[256], start[257], cur[256], sc[256];
  __shared__ float red[8];
  const int tid = threadIdx.x;
  const int b   = blockIdx.x;
  const int n0  = b * 256;

  if (tid < 256) hist[tid] = 0;
  __syncthreads();
  const int szc = min(gcur[b], BCAP);
  const int* __restrict__ pb = pk + (size_t)b * BCAP;
  for (int j = tid; j < szc; j += 512)
    atomicAdd(&hist[pb[j] >> 17], 1);
  __syncthreads();
  if (tid < 256) sc[tid] = hist[tid];
  __syncthreads();
  for (int d = 1; d < 256; d <<= 1) {
    int v = (tid < 256 && tid >= d) ? sc[tid - d] : 0;
    __syncthreads();
    if (tid < 256) sc[tid] += v;
    __syncthreads();
  }
  if (tid < 256) { start[tid] = tid ? sc[tid - 1] : 0; cur[tid] = start[tid]; }
  __syncthreads();
  if (tid == 0) start[256] = sc[255];
  __syncthreads();
  for (int j = tid; j < szc; j += 512) {
    int w = pb[j];
    int pos = atomicAdd(&cur[w >> 17], 1);
    csr[(size_t)b * BCAP + pos] = w & 0x1FFFF;
  }
  if (tid < 257) ro[b * 257 + tid] = start[tid];

  // global tight scale: s = max over rows of deg^-1/2 * max|x_row| (rmax precomputed)
  float tmax = 0.f;
  if (tid < 256) {
    int n = n0 + tid, dg = hist[tid];
    if (n < NN && dg > 0) tmax = rsqrtf((float)dg) * rmax[n];
  }
#pragma unroll
  for (int k = 1; k < 64; k <<= 1) tmax = fmaxf(tmax, __shfl_xor(tmax, k, 64));
  if ((tid & 63) == 0) red[tid >> 6] = tmax;
  __syncthreads();
  if (tid == 0) {
    float m = red[0];
#pragma unroll
    for (int w = 1; w < 8; ++w) m = fmaxf(m, red[w]);
    atomicMax(xm, __float_as_int(m));   // positive floats: int order == float order
  }
}

// ---------------- pack: y12[n] = int12x256( deg^-1/2 * x[n] / s ) --------------
__global__ __launch_bounds__(256) void k_pack(const float* __restrict__ x,
                                              const int* __restrict__ ro,
                                              const int* __restrict__ xm,
                                              unsigned* __restrict__ y12) {
  const int tid = threadIdx.x;
  const int row = blockIdx.x * 8 + (tid >> 5);   // 12500 * 8 = 100000 exact
  const int l32 = tid & 31;
  const int bkt = row >> 8, r = row & 255;
  const int deg = ro[bkt * 257 + r + 1] - ro[bkt * 257 + r];
  const float nr  = rsqrtf((float)deg);
  const float s   = __int_as_float(*xm);
  const float inv = 2047.0f / s;

  float4 a = ((const float4*)x)[(size_t)row * 64 + l32 * 2];
  float4 b = ((const float4*)x)[(size_t)row * 64 + l32 * 2 + 1];
  int q[8];
  float v[8] = {a.x, a.y, a.z, a.w, b.x, b.y, b.z, b.w};
#pragma unroll
  for (int c = 0; c < 8; ++c) {
    int t = (int)rintf(nr * v[c] * inv) + 2048;
    q[c] = min(4095, max(0, t));
  }
  U12 o;
  o.a = (unsigned)q[0] | ((unsigned)q[1] << 12) | ((unsigned)(q[2] & 0xFF) << 24);
  o.b = ((unsigned)q[2] >> 8) | ((unsigned)q[3] << 4) | ((unsigned)q[4] << 16) |
        ((unsigned)(q[5] & 0xF) << 28);
  o.c = ((unsigned)q[5] >> 4) | ((unsigned)q[6] << 8) | ((unsigned)q[7] << 20);
  ((U12*)y12)[(size_t)row * 32 + l32] = o;
}

// ---------------- fused: int12 gather-agg -> MFMA -> relu -> pooled max --------
// R6/R8-verified structure; ONLY change: asm liveness pin keeps all 8 gathered
// rows resident (compiler was serializing loads at VGPR=32 -> ~4 outstanding
// misses/wave; this forces 8-deep issue before the single waitcnt).
__global__ __launch_bounds__(512, 8) void k_fused4(const int* __restrict__ ro,
                                                   const int* __restrict__ csr,
                                                   const unsigned* __restrict__ y12,
                                                   const unsigned short* __restrict__ wbf,
                                                   const float* __restrict__ b1,
                                                   const int* __restrict__ batch,
                                                   const int* __restrict__ xm,
                                                   int* __restrict__ pooled) {
  __shared__ __align__(16) unsigned short As[16][264];
  __shared__ int rs[17];
  __shared__ int bg[16];
  const int tid  = threadIdx.x;
  const int n0   = blockIdx.x * 16;              // 6250 blocks * 16 = 100000 exact
  const int bkt  = blockIdx.x >> 4;              // 256-node bucket
  const int br   = (blockIdx.x & 15) * 16;       // bucket-local first row
  const int wave = tid >> 6;
  const int lane = tid & 63;

  if (tid < 17) rs[tid] = ro[bkt * 257 + br + tid];
  else if (tid >= 64 && tid < 80) bg[tid - 64] = batch[n0 + tid - 64];
  __syncthreads();

  const int half = lane >> 5, l32 = lane & 31;
  const int il   = wave * 2 + half;              // 0..15, block-local node
  const int i    = n0 + il;
  const U12* __restrict__ yr = (const U12*)y12;  // row = 32 x 12 B
  const int* __restrict__ ce = csr + (size_t)bkt * BCAP;
  const float s = __int_as_float(*xm);

  int acc[8];
#pragma unroll
  for (int c = 0; c < 8; ++c) acc[c] = 0;
#define UNP(V) do { unsigned w0 = (V).a, w1 = (V).b, w2 = (V).c;                  \
    acc[0] += (int)(w0 & 0xFFFu);                                                 \
    acc[1] += (int)((w0 >> 12) & 0xFFFu);                                         \
    acc[2] += (int)((w0 >> 24) | ((w1 & 0xFu) << 8));                             \
    acc[3] += (int)((w1 >> 4) & 0xFFFu);                                          \
    acc[4] += (int)((w1 >> 16) & 0xFFFu);                                         \
    acc[5] += (int)((w1 >> 28) | ((w2 & 0xFFu) << 4));                            \
    acc[6] += (int)((w2 >> 8) & 0xFFFu);                                          \
    acc[7] += (int)(w2 >> 20); } while (0)

  U12 sv = yr[(size_t)i * 32 + l32];             // self term
  UNP(sv);

  int e = rs[il];
  const int e1 = rs[il + 1];
  const int cnt = e1 - e + 1;
  const float ni = rsqrtf((float)(e1 - e));
  for (; e + 8 <= e1; e += 8) {
    int d0 = ce[e],     d1 = ce[e + 1], d2 = ce[e + 2], d3 = ce[e + 3];
    int d4 = ce[e + 4], d5 = ce[e + 5], d6 = ce[e + 6], d7 = ce[e + 7];
    U12 v0 = yr[(size_t)d0 * 32 + l32];
    U12 v1 = yr[(size_t)d1 * 32 + l32];
    U12 v2 = yr[(size_t)d2 * 32 + l32];
    U12 v3 = yr[(size_t)d3 * 32 + l32];
    U12 v4 = yr[(size_t)d4 * 32 + l32];
    U12 v5 = yr[(size_t)d5 * 32 + l32];
    U12 v6 = yr[(size_t)d6 * 32 + l32];
    U12 v7 = yr[(size_t)d7 * 32 + l32];
    // liveness pin: force all 8 rows (24 dwords) resident before unpacking ->
    // 8 loads issue back-to-back, ONE waitcnt, instead of serialized sub-batches
    asm volatile("" :: "v"(v0.a), "v"(v0.b), "v"(v0.c),
                       "v"(v1.a), "v"(v1.b), "v"(v1.c),
                       "v"(v2.a), "v"(v2.b), "v"(v2.c),
                       "v"(v3.a), "v"(v3.b), "v"(v3.c),
                       "v"(v4.a), "v"(v4.b), "v"(v4.c),
                       "v"(v5.a), "v"(v5.b), "v"(v5.c),
                       "v"(v6.a), "v"(v6.b), "v"(v6.c),
                       "v"(v7.a), "v"(v7.b), "v"(v7.c));
    UNP(v0); UNP(v1); UNP(v2); UNP(v3); UNP(v4); UNP(v5); UNP(v6); UNP(v7);
  }
  for (; e + 4 <= e1; e += 4) {
    int d0 = ce[e], d1 = ce[e + 1], d2 = ce[e + 2], d3 = ce[e + 3];
    U12 v0 = yr[(size_t)d0 * 32 + l32];
    U12 v1 = yr[(size_t)d1 * 32 + l32];
    U12 v2 = yr[(size_t)d2 * 32 + l32];
    U12 v3 = yr[(size_t)d3 * 32 + l32];
    asm volatile("" :: "v"(v0.a), "v"(v0.b), "v"(v0.c),
                       "v"(v1.a), "v"(v1.b), "v"(v1.c),
                       "v"(v2.a), "v"(v2.b), "v"(v2.c),
                       "v"(v3.a), "v"(v3.b), "v"(v3.c));
    UNP(v0); UNP(v1); UNP(v2); UNP(v3);
  }
  for (; e < e1; ++e) {
    U12 v = yr[(size_t)ce[e] * 32 + l32];
    UNP(v);
  }
#undef UNP
  const float fsc = ni * s * (1.0f / 2047.0f);
  const float boff = 2048.0f * (float)cnt;
  u16x8 o;
#pragma unroll
  for (int c = 0; c < 8; ++c) o[c] = f2b(fsc * ((float)acc[c] - boff));
  *(u16x8*)&As[il][l32 * 8] = o;
  __syncthreads();

  // ---- MFMA phase: wave w covers cols [w*32, w*32+32) of the 16x256 tile ----
  const int r16 = lane & 15, quad = lane >> 4;
  f32x4 acc4[2];
#pragma unroll
  for (int t = 0; t < 2; ++t) acc4[t] = (f32x4){0.f, 0.f, 0.f, 0.f};
  for (int kc = 0; kc < 8; ++kc) {
    bf16x8 af = *(const bf16x8*)&As[r16][kc * 32 + quad * 8];
#pragma unroll
    for (int ct = 0; ct < 2; ++ct) {
      const int n = wave * 32 + ct * 16 + r16;
      bf16x8 bf = *(const bf16x8*)(wbf + (size_t)n * 256 + kc * 32 + quad * 8);
      acc4[ct] = __builtin_amdgcn_mfma_f32_16x16x32_bf16(af, bf, acc4[ct], 0, 0, 0);
    }
  }

  // ---- epilogue: bias + relu + per-graph column max + atomicMax ----
  const int g0 = bg[0], g15 = bg[15];
  if (g0 == g15) {
#pragma unroll
    for (int ct = 0; ct < 2; ++ct) {
      const int col = wave * 32 + ct * 16 + r16;
      const float bias = b1[col];
      float m = 0.f;   // relu identity
#pragma unroll
      for (int r = 0; r < 4; ++r) m = fmaxf(m, acc4[ct][r] + bias);
      m = fmaxf(m, __shfl_xor(m, 16, 64));
      m = fmaxf(m, __shfl_xor(m, 32, 64));
      if (quad == 0) atomicMax(&pooled[g0 * 256 + col], __float_as_int(m));
    }
  } else {
#pragma unroll
    for (int ct = 0; ct < 2; ++ct) {
      const int col = wave * 32 + ct * 16 + r16;
      const float bias = b1[col];
      for (int g = g0; g <= g15; ++g) {
        float m = 0.f;
#pragma unroll
        for (int r = 0; r < 4; ++r) {
          const int row = quad * 4 + r;
          float v = fmaxf(acc4[ct][r] + bias, 0.f);
          if (bg[row] == g) m = fmaxf(m, v);
        }
        m = fmaxf(m, __shfl_xor(m, 16, 64));
        m = fmaxf(m, __shfl_xor(m, 32, 64));
        if (quad == 0) atomicMax(&pooled[g * 256 + col], __float_as_int(m));
      }
    }
  }
}

// ---------------- out = pooled @ W2^T + b2 ----------------
__global__ void k_out(const float* __restrict__ pooled, const float* __restrict__ w2,
                      const float* __restrict__ b2, float* __restrict__ out) {
  const int wave = threadIdx.x >> 6;
  const int lane = threadIdx.x & 63;
  const int g = blockIdx.x * 4 + wave;
  float4 p = ((const float4*)pooled)[g * 64 + lane];
  float4 w = ((const float4*)w2)[lane];
  float s = p.x * w.x + p.y * w.y + p.z * w.z + p.w * w.w;
  for (int off = 32; off; off >>= 1) s += __shfl_down(s, off, 64);
  if (lane == 0) out[g] = s + b2[0];
}

extern "C" void kernel_launch(void* const* d_in, const int* in_sizes, int n_in,
                              void* d_out, int out_size, void* d_ws, size_t ws_size,
                              hipStream_t stream) {
  const float* x     = (const float*)d_in[0];
  const int*   ei    = (const int*)d_in[1];
  const int*   batch = (const int*)d_in[2];
  const float* W1    = (const float*)d_in[3];
  const float* b1    = (const float*)d_in[4];
  const float* W2    = (const float*)d_in[5];
  const float* b2    = (const float*)d_in[6];
  const int* src = ei;
  const int* dst = ei + EE;
  float* out = (float*)d_out;

  // workspace carve (256B aligned)
  size_t off = 0;
  auto carve = [&](size_t bytes) -> void* {
    void* p = (char*)d_ws + off;
    off += (bytes + 255) & ~(size_t)255;
    return p;
  };
  int*   pooled = (int*)carve((size_t)GG * 256 * 4);       // fp32 bit patterns
  int*   gcur   = (int*)carve((size_t)NBK2 * 4);           // bucket counts
  int*   xm     = (int*)carve(4);                          // global y absmax (f32 bits)
  const size_t zlen = off;                                  // one memset covers all 3
  unsigned* y12 = (unsigned*)carve((size_t)NN * 96 * 4);   // int12-packed y rows (384 B)
  int*   pk     = (int*)carve((size_t)NBK2 * BCAP * 4);    // bucket-sorted edges
  int*   csr    = (int*)carve((size_t)NBK2 * BCAP * 4);    // node-grouped dst lists
  int*   ro     = (int*)carve((size_t)NBK2 * 257 * 4);     // per-bucket row offsets
  float* rmax   = (float*)carve((size_t)NN * 4);           // per-row max|x|
  unsigned short* wbf = (unsigned short*)carve(256 * 256 * 2);

  hipMemsetAsync(pooled, 0, zlen, stream);   // pooled zeros + cursors + xm

  k_rmax <<<NN / 16,            256,  0, stream>>>(x, W1, rmax, wbf);
  k_split<<<(EE + TT - 1) / TT, 1024, 0, stream>>>(src, dst, gcur, pk);
  k_prep <<<NBK2,               512,  0, stream>>>(gcur, pk, rmax, csr, ro, xm);
  k_pack <<<NN / 8,             256,  0, stream>>>(x, ro, xm, y12);
  k_fused4<<<NN / 16,           512,  0, stream>>>(ro, csr, y12, wbf, b1, batch, xm, pooled);
  k_out  <<<GG / 4,             256,  0, stream>>>((const float*)pooled, W2, b2, out);
}

// Round 10
// 438.299 us; speedup vs baseline: 1.0244x; 1.0244x over previous
//
#include <hip/hip_runtime.h>
#include <cstddef>

#define NN    100000
#define EE    3200000
#define GG    512
#define NBK2  391          // buckets of 256 nodes (single-pass sort)
#define BCAP  9216         // bucket capacity: mean 8192, +11 sigma
#define TT    4096         // LDS sort tile (edges)

typedef __attribute__((ext_vector_type(8))) short bf16x8;
typedef __attribute__((ext_vector_type(4))) float f32x4;
typedef __attribute__((ext_vector_type(8))) unsigned short u16x8;

struct U12 { unsigned a, b, c; };   // 12 B: 8 chans x 12-bit

static __device__ __forceinline__ unsigned short f2b(float f) {
  unsigned u = __float_as_uint(f);
  unsigned r = u + 0x7fffu + ((u >> 16) & 1u);   // RNE
  return (unsigned short)(r >> 16);
}

// ---------------- single-pass sort: edges -> 391 buckets, 1 tile per block -----
__global__ __launch_bounds__(1024, 2) void k_split(const int* __restrict__ src,
                                                   const int* __restrict__ dst,
                                                   int* __restrict__ gcur,
                                                   int* __restrict__ pk) {
  __shared__ int hist[NBK2], st[NBK2], cur[NBK2], gbase[NBK2];
  __shared__ int sc[512];
  __shared__ int sorted[TT];
  __shared__ unsigned short binof[TT];
  const int tid = threadIdx.x;
  const int t0  = blockIdx.x * TT;
  const int tc  = min(TT, EE - t0);

  if (tid < NBK2) hist[tid] = 0;
  __syncthreads();
  int myk[4], myw[4];
#pragma unroll
  for (int r = 0; r < 4; ++r) {
    int j = r * 1024 + tid;
    myk[r] = -1;
    if (j < tc) {
      int s = src[t0 + j], d = dst[t0 + j];
      myk[r] = s >> 8;                        // bucket of 256 nodes
      myw[r] = ((s & 255) << 17) | d;         // (src_local8, dst17)
      atomicAdd(&hist[myk[r]], 1);
    }
  }
  __syncthreads();
  if (tid < 512) sc[tid] = (tid < NBK2) ? hist[tid] : 0;
  __syncthreads();
  for (int d = 1; d < 512; d <<= 1) {
    int v = (tid < 512 && tid >= d) ? sc[tid - d] : 0;
    __syncthreads();
    if (tid < 512) sc[tid] += v;
    __syncthreads();
  }
  if (tid < NBK2) { st[tid] = tid ? sc[tid - 1] : 0; cur[tid] = st[tid]; }
  __syncthreads();
#pragma unroll
  for (int r = 0; r < 4; ++r) {
    if (myk[r] >= 0) {
      int pos = atomicAdd(&cur[myk[r]], 1);
      sorted[pos] = myw[r];
      binof[pos] = (unsigned short)myk[r];
    }
  }
  __syncthreads();
  if (tid < NBK2) {
    int c = cur[tid] - st[tid];
    gbase[tid] = c ? atomicAdd(&gcur[tid], c) : 0;
  }
  __syncthreads();
  for (int j = tid; j < tc; j += 1024) {
    int k   = binof[j];
    int idx = gbase[k] + (j - st[k]);
    if (idx < BCAP) pk[(size_t)k * BCAP + idx] = sorted[j];
  }
}

// ---------------- per-bucket prep: csr + ro + xm + W1->bf16 (1024 threads) -----
// R6 structure; thread count 512 -> 1024 halves the serial round count of both
// pk passes and the x-scan (391 blocks is fixed by bucket count -> per-block
// serial work is the lever).
__global__ __launch_bounds__(1024) void k_prep(const int* __restrict__ gcur,
                                               const int* __restrict__ pk,
                                               const float* __restrict__ x,
                                               const float* __restrict__ w1,
                                               unsigned short* __restrict__ wbf,
                                               int* __restrict__ csr,
                                               int* __restrict__ ro,
                                               int* __restrict__ xm) {
  __shared__ int hist[256], start[257], cur[256], sc[256];
  __shared__ float red[16];
  const int tid = threadIdx.x;
  const int b   = blockIdx.x;
  const int n0  = b * 256;

  if (tid < 256) hist[tid] = 0;
  __syncthreads();
  const int szc = min(gcur[b], BCAP);
  const int* __restrict__ pb = pk + (size_t)b * BCAP;
  for (int j = tid; j < szc; j += 1024)
    atomicAdd(&hist[pb[j] >> 17], 1);
  __syncthreads();
  if (tid < 256) sc[tid] = hist[tid];
  __syncthreads();
  for (int d = 1; d < 256; d <<= 1) {
    int v = (tid < 256 && tid >= d) ? sc[tid - d] : 0;
    __syncthreads();
    if (tid < 256) sc[tid] += v;
    __syncthreads();
  }
  if (tid < 256) { start[tid] = tid ? sc[tid - 1] : 0; cur[tid] = start[tid]; }
  __syncthreads();
  if (tid == 0) start[256] = sc[255];
  __syncthreads();
  for (int j = tid; j < szc; j += 1024) {
    int w = pb[j];
    int pos = atomicAdd(&cur[w >> 17], 1);
    csr[(size_t)b * BCAP + pos] = w & 0x1FFFF;
  }
  if (tid < 257) ro[b * 257 + tid] = start[tid];
  __syncthreads();

  // global tight scale: s = max over rows of deg^-1/2 * max|x_row|
  float tmax = 0.f;
  for (int it = 0; it < 16; ++it) {
    int idx = it * 1024 + tid;         // 256 rows x 64 float4
    int row = idx >> 6, c4 = idx & 63;
    int n = n0 + row;
    int deg = start[row + 1] - start[row];
    if (n < NN && deg > 0) {
      float nr = rsqrtf((float)deg);
      float4 v = ((const float4*)x)[(size_t)n * 64 + c4];
      float m = fmaxf(fmaxf(fabsf(v.x), fabsf(v.y)), fmaxf(fabsf(v.z), fabsf(v.w)));
      tmax = fmaxf(tmax, nr * m);
    }
  }
#pragma unroll
  for (int k = 1; k < 64; k <<= 1) tmax = fmaxf(tmax, __shfl_xor(tmax, k, 64));
  if ((tid & 63) == 0) red[tid >> 6] = tmax;
  __syncthreads();
  if (tid == 0) {
    float m = red[0];
#pragma unroll
    for (int w = 1; w < 16; ++w) m = fmaxf(m, red[w]);
    atomicMax(xm, __float_as_int(m));   // positive floats: int order == float order
  }

  if (b < 32 && tid < 512) {           // W1 -> bf16 (32 blocks x 512 float4)
    int i = b * 512 + tid;
    float4 v = ((const float4*)w1)[i];
    ushort4 o;
    o.x = f2b(v.x); o.y = f2b(v.y); o.z = f2b(v.z); o.w = f2b(v.w);
    ((ushort4*)wbf)[i] = o;
  }
}

// ---------------- pack: y12[n] = int12x256( deg^-1/2 * x[n] / s ) --------------
__global__ __launch_bounds__(256) void k_pack(const float* __restrict__ x,
                                              const int* __restrict__ ro,
                                              const int* __restrict__ xm,
                                              unsigned* __restrict__ y12) {
  const int tid = threadIdx.x;
  const int row = blockIdx.x * 8 + (tid >> 5);   // 12500 * 8 = 100000 exact
  const int l32 = tid & 31;
  const int bkt = row >> 8, r = row & 255;
  const int deg = ro[bkt * 257 + r + 1] - ro[bkt * 257 + r];
  const float nr  = rsqrtf((float)deg);
  const float s   = __int_as_float(*xm);
  const float inv = 2047.0f / s;

  float4 a = ((const float4*)x)[(size_t)row * 64 + l32 * 2];
  float4 b = ((const float4*)x)[(size_t)row * 64 + l32 * 2 + 1];
  int q[8];
  float v[8] = {a.x, a.y, a.z, a.w, b.x, b.y, b.z, b.w};
#pragma unroll
  for (int c = 0; c < 8; ++c) {
    int t = (int)rintf(nr * v[c] * inv) + 2048;
    q[c] = min(4095, max(0, t));
  }
  U12 o;
  o.a = (unsigned)q[0] | ((unsigned)q[1] << 12) | ((unsigned)(q[2] & 0xFF) << 24);
  o.b = ((unsigned)q[2] >> 8) | ((unsigned)q[3] << 4) | ((unsigned)q[4] << 16) |
        ((unsigned)(q[5] & 0xF) << 28);
  o.c = ((unsigned)q[5] >> 4) | ((unsigned)q[6] << 8) | ((unsigned)q[7] << 20);
  ((U12*)y12)[(size_t)row * 32 + l32] = o;
}

// ---------------- fused: int12 gather-agg -> MFMA -> relu -> pooled max --------
// R6-verified kernel, byte-identical (pin reverted).
__global__ __launch_bounds__(512, 8) void k_fused4(const int* __restrict__ ro,
                                                   const int* __restrict__ csr,
                                                   const unsigned* __restrict__ y12,
                                                   const unsigned short* __restrict__ wbf,
                                                   const float* __restrict__ b1,
                                                   const int* __restrict__ batch,
                                                   const int* __restrict__ xm,
                                                   int* __restrict__ pooled) {
  __shared__ __align__(16) unsigned short As[16][264];
  __shared__ int rs[17];
  __shared__ int bg[16];
  const int tid  = threadIdx.x;
  const int n0   = blockIdx.x * 16;              // 6250 blocks * 16 = 100000 exact
  const int bkt  = blockIdx.x >> 4;              // 256-node bucket
  const int br   = (blockIdx.x & 15) * 16;       // bucket-local first row
  const int wave = tid >> 6;
  const int lane = tid & 63;

  if (tid < 17) rs[tid] = ro[bkt * 257 + br + tid];
  else if (tid >= 64 && tid < 80) bg[tid - 64] = batch[n0 + tid - 64];
  __syncthreads();

  const int half = lane >> 5, l32 = lane & 31;
  const int il   = wave * 2 + half;              // 0..15, block-local node
  const int i    = n0 + il;
  const U12* __restrict__ yr = (const U12*)y12;  // row = 32 x 12 B
  const int* __restrict__ ce = csr + (size_t)bkt * BCAP;
  const float s = __int_as_float(*xm);

  int acc[8];
#pragma unroll
  for (int c = 0; c < 8; ++c) acc[c] = 0;
#define UNP(V) do { unsigned w0 = (V).a, w1 = (V).b, w2 = (V).c;                  \
    acc[0] += (int)(w0 & 0xFFFu);                                                 \
    acc[1] += (int)((w0 >> 12) & 0xFFFu);                                         \
    acc[2] += (int)((w0 >> 24) | ((w1 & 0xFu) << 8));                             \
    acc[3] += (int)((w1 >> 4) & 0xFFFu);                                          \
    acc[4] += (int)((w1 >> 16) & 0xFFFu);                                         \
    acc[5] += (int)((w1 >> 28) | ((w2 & 0xFFu) << 4));                            \
    acc[6] += (int)((w2 >> 8) & 0xFFFu);                                          \
    acc[7] += (int)(w2 >> 20); } while (0)

  U12 sv = yr[(size_t)i * 32 + l32];             // self term
  UNP(sv);

  int e = rs[il];
  const int e1 = rs[il + 1];
  const int cnt = e1 - e + 1;
  const float ni = rsqrtf((float)(e1 - e));
  for (; e + 8 <= e1; e += 8) {
    int d0 = ce[e],     d1 = ce[e + 1], d2 = ce[e + 2], d3 = ce[e + 3];
    int d4 = ce[e + 4], d5 = ce[e + 5], d6 = ce[e + 6], d7 = ce[e + 7];
    U12 v0 = yr[(size_t)d0 * 32 + l32];
    U12 v1 = yr[(size_t)d1 * 32 + l32];
    U12 v2 = yr[(size_t)d2 * 32 + l32];
    U12 v3 = yr[(size_t)d3 * 32 + l32];
    U12 v4 = yr[(size_t)d4 * 32 + l32];
    U12 v5 = yr[(size_t)d5 * 32 + l32];
    U12 v6 = yr[(size_t)d6 * 32 + l32];
    U12 v7 = yr[(size_t)d7 * 32 + l32];
    UNP(v0); UNP(v1); UNP(v2); UNP(v3); UNP(v4); UNP(v5); UNP(v6); UNP(v7);
  }
  for (; e + 4 <= e1; e += 4) {
    int d0 = ce[e], d1 = ce[e + 1], d2 = ce[e + 2], d3 = ce[e + 3];
    U12 v0 = yr[(size_t)d0 * 32 + l32];
    U12 v1 = yr[(size_t)d1 * 32 + l32];
    U12 v2 = yr[(size_t)d2 * 32 + l32];
    U12 v3 = yr[(size_t)d3 * 32 + l32];
    UNP(v0); UNP(v1); UNP(v2); UNP(v3);
  }
  for (; e < e1; ++e) {
    U12 v = yr[(size_t)ce[e] * 32 + l32];
    UNP(v);
  }
#undef UNP
  const float fsc = ni * s * (1.0f / 2047.0f);
  const float boff = 2048.0f * (float)cnt;
  u16x8 o;
#pragma unroll
  for (int c = 0; c < 8; ++c) o[c] = f2b(fsc * ((float)acc[c] - boff));
  *(u16x8*)&As[il][l32 * 8] = o;
  __syncthreads();

  // ---- MFMA phase: wave w covers cols [w*32, w*32+32) of the 16x256 tile ----
  const int r16 = lane & 15, quad = lane >> 4;
  f32x4 acc4[2];
#pragma unroll
  for (int t = 0; t < 2; ++t) acc4[t] = (f32x4){0.f, 0.f, 0.f, 0.f};
  for (int kc = 0; kc < 8; ++kc) {
    bf16x8 af = *(const bf16x8*)&As[r16][kc * 32 + quad * 8];
#pragma unroll
    for (int ct = 0; ct < 2; ++ct) {
      const int n = wave * 32 + ct * 16 + r16;
      bf16x8 bf = *(const bf16x8*)(wbf + (size_t)n * 256 + kc * 32 + quad * 8);
      acc4[ct] = __builtin_amdgcn_mfma_f32_16x16x32_bf16(af, bf, acc4[ct], 0, 0, 0);
    }
  }

  // ---- epilogue: bias + relu + per-graph column max + atomicMax ----
  const int g0 = bg[0], g15 = bg[15];
  if (g0 == g15) {
#pragma unroll
    for (int ct = 0; ct < 2; ++ct) {
      const int col = wave * 32 + ct * 16 + r16;
      const float bias = b1[col];
      float m = 0.f;   // relu identity
#pragma unroll
      for (int r = 0; r < 4; ++r) m = fmaxf(m, acc4[ct][r] + bias);
      m = fmaxf(m, __shfl_xor(m, 16, 64));
      m = fmaxf(m, __shfl_xor(m, 32, 64));
      if (quad == 0) atomicMax(&pooled[g0 * 256 + col], __float_as_int(m));
    }
  } else {
#pragma unroll
    for (int ct = 0; ct < 2; ++ct) {
      const int col = wave * 32 + ct * 16 + r16;
      const float bias = b1[col];
      for (int g = g0; g <= g15; ++g) {
        float m = 0.f;
#pragma unroll
        for (int r = 0; r < 4; ++r) {
          const int row = quad * 4 + r;
          float v = fmaxf(acc4[ct][r] + bias, 0.f);
          if (bg[row] == g) m = fmaxf(m, v);
        }
        m = fmaxf(m, __shfl_xor(m, 16, 64));
        m = fmaxf(m, __shfl_xor(m, 32, 64));
        if (quad == 0) atomicMax(&pooled[g * 256 + col], __float_as_int(m));
      }
    }
  }
}

// ---------------- out = pooled @ W2^T + b2 ----------------
__global__ void k_out(const float* __restrict__ pooled, const float* __restrict__ w2,
                      const float* __restrict__ b2, float* __restrict__ out) {
  const int wave = threadIdx.x >> 6;
  const int lane = threadIdx.x & 63;
  const int g = blockIdx.x * 4 + wave;
  float4 p = ((const float4*)pooled)[g * 64 + lane];
  float4 w = ((const float4*)w2)[lane];
  float s = p.x * w.x + p.y * w.y + p.z * w.z + p.w * w.w;
  for (int off = 32; off; off >>= 1) s += __shfl_down(s, off, 64);
  if (lane == 0) out[g] = s + b2[0];
}

extern "C" void kernel_launch(void* const* d_in, const int* in_sizes, int n_in,
                              void* d_out, int out_size, void* d_ws, size_t ws_size,
                              hipStream_t stream) {
  const float* x     = (const float*)d_in[0];
  const int*   ei    = (const int*)d_in[1];
  const int*   batch = (const int*)d_in[2];
  const float* W1    = (const float*)d_in[3];
  const float* b1    = (const float*)d_in[4];
  const float* W2    = (const float*)d_in[5];
  const float* b2    = (const float*)d_in[6];
  const int* src = ei;
  const int* dst = ei + EE;
  float* out = (float*)d_out;

  // workspace carve (256B aligned)
  size_t off = 0;
  auto carve = [&](size_t bytes) -> void* {
    void* p = (char*)d_ws + off;
    off += (bytes + 255) & ~(size_t)255;
    return p;
  };
  int*   pooled = (int*)carve((size_t)GG * 256 * 4);       // fp32 bit patterns
  int*   gcur   = (int*)carve((size_t)NBK2 * 4);           // bucket counts
  int*   xm     = (int*)carve(4);                          // global y absmax (f32 bits)
  const size_t zlen = off;                                  // one memset covers all 3
  unsigned* y12 = (unsigned*)carve((size_t)NN * 96 * 4);   // int12-packed y rows (384 B)
  int*   pk     = (int*)carve((size_t)NBK2 * BCAP * 4);    // bucket-sorted edges
  int*   csr    = (int*)carve((size_t)NBK2 * BCAP * 4);    // node-grouped dst lists
  int*   ro     = (int*)carve((size_t)NBK2 * 257 * 4);     // per-bucket row offsets
  unsigned short* wbf = (unsigned short*)carve(256 * 256 * 2);

  hipMemsetAsync(pooled, 0, zlen, stream);   // pooled zeros + cursors + xm

  k_split<<<(EE + TT - 1) / TT, 1024, 0, stream>>>(src, dst, gcur, pk);
  k_prep <<<NBK2,               1024, 0, stream>>>(gcur, pk, x, W1, wbf, csr, ro, xm);
  k_pack <<<NN / 8,             256,  0, stream>>>(x, ro, xm, y12);
  k_fused4<<<NN / 16,           512,  0, stream>>>(ro, csr, y12, wbf, b1, batch, xm, pooled);
  k_out  <<<GG / 4,             256,  0, stream>>>((const float*)pooled, W2, b2, out);
}